// Round 7
// baseline (651.194 us; speedup 1.0000x reference)
//
#include <hip/hip_runtime.h>
#include <hip/hip_bf16.h>
#include <hip/hip_fp16.h>

typedef __attribute__((ext_vector_type(4))) float f32x4;
typedef __attribute__((ext_vector_type(8))) __bf16 bf16x8;
typedef __attribute__((ext_vector_type(8))) unsigned short u16x8;
typedef unsigned int u32;
typedef unsigned short u16;

// ---------- helpers ----------
__device__ __forceinline__ void gload_lds16(const void* g, void* l) {
  __builtin_amdgcn_global_load_lds((const u32 __attribute__((address_space(1)))*)g,
                                   (u32 __attribute__((address_space(3)))*)l, 16, 0, 0);
}
__device__ __forceinline__ u16 f2bf(float f) {           // exact for small integers
  union { float f; u32 u; } c; c.f = f; return (u16)(c.u >> 16);
}
__device__ __forceinline__ float h2f(u16 u) { return __half2float(__ushort_as_half(u)); }
__device__ __forceinline__ u16  f2h(float f){ return __half_as_ushort(__float2half_rn(f)); }

// ---------- 1. per-token RMS-norm + absmax int8 quant of x (stored as bf16 ints) ----------
__global__ __launch_bounds__(256) void quant_x_kernel(const float* __restrict__ x,
    u16* __restrict__ qx, float* __restrict__ invs) {
  const int D = 2048;
  int row = blockIdx.x, tid = threadIdx.x;
  const float* xr = x + (size_t)row * D;
  float4 a = ((const float4*)xr)[tid * 2], b = ((const float4*)xr)[tid * 2 + 1];
  float v[8] = {a.x, a.y, a.z, a.w, b.x, b.y, b.z, b.w};
  double ss = 0; float mx = 0.0f;
#pragma unroll
  for (int i = 0; i < 8; i++) { ss += (double)v[i] * v[i]; mx = fmaxf(mx, fabsf(v[i])); }
  __shared__ double sd[256]; __shared__ float sf[256];
  sd[tid] = ss; sf[tid] = mx; __syncthreads();
  for (int o = 128; o > 0; o >>= 1) {
    if (tid < o) { sd[tid] += sd[tid + o]; sf[tid] = fmaxf(sf[tid], sf[tid + o]); }
    __syncthreads();
  }
  __shared__ float bn, bs;
  if (tid == 0) {
    float n = fmaxf((float)sqrt(sd[0]), 1e-12f);
    float amax = sf[0] * (sqrtf((float)D) / n);
    float cl = fmaxf(amax, 1e-5f);
    bn = n; bs = 127.0f / cl;
    invs[row] = cl / 127.0f;
  }
  __syncthreads();
  float n = bn, s = bs, sq = sqrtf((float)D);
  u16x8 q;
#pragma unroll
  for (int i = 0; i < 8; i++) {
    float xn = (v[i] / n) * sq;
    float r = rintf(xn * s);
    r = fminf(fmaxf(r, -128.0f), 127.0f);
    q[i] = f2bf(r);
  }
  *(u16x8*)&qx[(size_t)row * D + tid * 8] = q;
}

// ---------- 2. deterministic sum(|w|) partials ----------
__global__ __launch_bounds__(256) void absum_partial(const float* __restrict__ w,
    double* __restrict__ part, int n4) {
  int tid = threadIdx.x;
  double s = 0;
  for (int i = blockIdx.x * 256 + tid; i < n4; i += gridDim.x * 256) {
    float4 v = ((const float4*)w)[i];
    s += (double)fabsf(v.x) + (double)fabsf(v.y) + (double)fabsf(v.z) + (double)fabsf(v.w);
  }
  __shared__ double sd[256];
  sd[tid] = s; __syncthreads();
  for (int o = 128; o > 0; o >>= 1) { if (tid < o) sd[tid] += sd[tid + o]; __syncthreads(); }
  if (tid == 0) part[blockIdx.x] = sd[0];
}

__global__ __launch_bounds__(256) void wscale_final(const double* __restrict__ part,
    float* __restrict__ wsc) {
  int tid = threadIdx.x;
  __shared__ double sd[256];
  sd[tid] = part[tid] + part[tid + 256]; __syncthreads();
  for (int o = 128; o > 0; o >>= 1) { if (tid < o) sd[tid] += sd[tid + o]; __syncthreads(); }
  double s1 = sd[0]; __syncthreads();
  sd[tid] = part[512 + tid] + part[768 + tid]; __syncthreads();
  for (int o = 128; o > 0; o >>= 1) { if (tid < o) sd[tid] += sd[tid + o]; __syncthreads(); }
  if (tid == 0) {
    float m1 = (float)(s1 / 16777216.0);
    float m2 = (float)(sd[0] / 16777216.0);
    float d1 = fmaxf(m1, 1e-5f), d2 = fmaxf(m2, 1e-5f);
    wsc[0] = 1.0f / d1; wsc[1] = d1; wsc[2] = 1.0f / d2; wsc[3] = d2;
  }
}

// ---------- 3. ternary weight quant (stored as bf16 {-1,0,1}) ----------
__global__ __launch_bounds__(256) void quant_w_kernel(const float* __restrict__ w,
    u16* __restrict__ q, const float* __restrict__ wsc, int widx, int n4) {
  float s = wsc[widx];
  for (int i = blockIdx.x * 256 + threadIdx.x; i < n4; i += gridDim.x * 256) {
    float4 v = ((const float4*)w)[i];
    ushort4 o;
    o.x = f2bf(fminf(fmaxf(rintf(v.x * s), -1.0f), 1.0f));
    o.y = f2bf(fminf(fmaxf(rintf(v.y * s), -1.0f), 1.0f));
    o.z = f2bf(fminf(fmaxf(rintf(v.z * s), -1.0f), 1.0f));
    o.w = f2bf(fminf(fmaxf(rintf(v.w * s), -1.0f), 1.0f));
    ((ushort4*)q)[i] = o;
  }
}

// ---------- 4. 256x256 GEMM, fine read/MFMA interleave on batch-granular vmcnt ledger ----------
// A[M][K] x B[N][K], bf16-int. Wave grid 2Mx4N, per-wave tile 128x64, BK=64.
// Quadrant order P0(alo,blo) P1(alo,bhi) P2(ahi,blo) P3(ahi,bhi): the final
// quadrant is disjoint from the next-tile {alo,blo} preloads, so the 12
// next-tile reads fly under P3's MFMAs.  Per tile:
//   read bhi | P0 | read ahi | P1 | lgkm(0)+bar | stage(t+2) | P2 |
//   vmcnt(8)+bar | read alo/blo(t+1) | P3
// Sync ledger identical to the passing r5/r6 kernels (batch-multiple vmcnt
// waits, fused waitcnt+s_barrier asm, batches separated by asm fences).
// EPI==0: dequant + exact GELU -> f16 store.  EPI==1: dequant -> f32 store.
template <int EPI>
__global__ __launch_bounds__(512, 2) void gemm_fi(const u16* __restrict__ A,
    const u16* __restrict__ B, int N, int K, int gridN,
    const float* __restrict__ rowscale, const float* __restrict__ wsc,
    int widx, void* __restrict__ outp) {
  __shared__ __align__(16) u16 sm[2][2][16384];   // [buf][mat][256*64] = 128 KiB
  const int tid = threadIdx.x;
  const int lane = tid & 63, w = tid >> 6;
  const int wm = w >> 2, wn = w & 3;            // 2M x 4N wave grid
  const int llo = lane & 15, lhi = lane >> 4;
  const int sw = llo & 7;                        // read-side swizzle (row&7 == llo&7)

  // T1: bijective XCD swizzle (gridDim.x % 8 == 0)
  const int nwg = gridDim.x;
  const int cpx = nwg >> 3;
  const int swz = (blockIdx.x & 7) * cpx + (blockIdx.x >> 3);
  const int bm = swz / gridN, bn = swz % gridN;

  const int NT = K >> 6;
  const size_t Abase = (size_t)(bm * 256) * K;
  const size_t Bbase = (size_t)(bn * 256) * K;

  // staging: thread covers 16B blocks P0, P1 of a 128x64 half-tile (inverse-swizzled source)
  const int Pa = tid, Pb = 512 + tid;
  const int r0s = Pa >> 3, r1s = Pb >> 3;
  const int kb0 = (Pa & 7) ^ (r0s & 7), kb1 = (Pb & 7) ^ (r1s & 7);

  auto stage = [&](int mat, int buf, int hf, int kt) {
    const u16* G = (mat == 0) ? A : B;
    size_t gb = ((mat == 0) ? Abase : Bbase) + (size_t)(hf * 128) * K + (size_t)kt * 64;
    u16* dst = &sm[buf][mat][hf * 8192];
    gload_lds16(G + gb + (size_t)r0s * K + kb0 * 8, dst + (size_t)Pa * 8);
    gload_lds16(G + gb + (size_t)r1s * K + kb1 * 8, dst + (size_t)Pb * 8);
  };

  bf16x8 alo[4][2], ahi[4][2], blo[2][2], bhi[2][2];
  auto readA = [&](int buf, int half, bf16x8 (&dst)[4][2]) {
    int rbase = wm * 128 + half * 64 + llo;
#pragma unroll
    for (int f = 0; f < 4; f++)
#pragma unroll
      for (int ks = 0; ks < 2; ks++)
        dst[f][ks] = *(const bf16x8*)&sm[buf][0][(rbase + f * 16) * 64 + ((((ks << 2) + lhi) ^ sw) << 3)];
  };
  auto readB = [&](int buf, int half, bf16x8 (&dst)[2][2]) {
    int rbase = wn * 64 + half * 32 + llo;
#pragma unroll
    for (int f = 0; f < 2; f++)
#pragma unroll
      for (int ks = 0; ks < 2; ks++)
        dst[f][ks] = *(const bf16x8*)&sm[buf][1][(rbase + f * 16) * 64 + ((((ks << 2) + lhi) ^ sw) << 3)];
  };

  f32x4 acc[8][4];
#pragma unroll
  for (int m = 0; m < 8; m++)
#pragma unroll
    for (int n = 0; n < 4; n++) acc[m][n] = (f32x4){0.f, 0.f, 0.f, 0.f};

  auto mmaq = [&](bf16x8 (&av)[4][2], bf16x8 (&bv)[2][2], int mh, int nh) {
    __builtin_amdgcn_s_setprio(1);
#pragma unroll
    for (int m = 0; m < 4; m++)
#pragma unroll
      for (int n = 0; n < 2; n++)
#pragma unroll
        for (int ks = 0; ks < 2; ks++)
          acc[mh * 4 + m][nh * 2 + n] =
              __builtin_amdgcn_mfma_f32_16x16x32_bf16(av[m][ks], bv[n][ks],
                                                      acc[mh * 4 + m][nh * 2 + n], 0, 0, 0);
    __builtin_amdgcn_s_setprio(0);
  };

  // prologue: tile0 batch, fence, tile1 batch; retire tile0 as a whole.
  stage(0, 0, 0, 0); stage(0, 0, 1, 0); stage(1, 0, 0, 0); stage(1, 0, 1, 0);
  asm volatile("s_nop 0" ::: "memory");            // batch boundary fence
  stage(0, 1, 0, 1); stage(0, 1, 1, 1); stage(1, 1, 0, 1); stage(1, 1, 1, 1);
  asm volatile("s_waitcnt vmcnt(8)\n\ts_barrier" ::: "memory");   // tile0 fully in LDS
  readA(0, 0, alo); readB(0, 0, blo);              // first-half operands of tile 0

  for (int t = 0; t < NT; t++) {
    const int cur = t & 1;
    readB(cur, 1, bhi);                            // 4 reads under P0
    __builtin_amdgcn_sched_barrier(0);
    mmaq(alo, blo, 0, 0);                          // P0 (lo,lo)
    __builtin_amdgcn_sched_barrier(0);
    readA(cur, 1, ahi);                            // 8 reads under P1
    __builtin_amdgcn_sched_barrier(0);
    mmaq(alo, bhi, 0, 1);                          // P1 (lo,hi)
    // all reads of buf[cur] drained across all waves before anyone overwrites it
    asm volatile("s_waitcnt lgkmcnt(0)\n\ts_barrier" ::: "memory");
    if (t + 2 < NT) {                               // stage tile t+2 (8 loads, any order)
      stage(0, cur, 0, t + 2); stage(1, cur, 0, t + 2);
      stage(0, cur, 1, t + 2); stage(1, cur, 1, t + 2);
    }
    mmaq(ahi, blo, 1, 0);                          // P2 (hi,lo) — last use of alo/blo
    __builtin_amdgcn_sched_barrier(0);
    if (t + 1 < NT) {                               // retire batch t+1 as a whole
      if (t + 2 < NT) asm volatile("s_waitcnt vmcnt(8)\n\ts_barrier" ::: "memory");
      else            asm volatile("s_waitcnt vmcnt(0)\n\ts_barrier" ::: "memory");
      // next-tile first-half operands (12 reads), in flight under P3
      readA(cur ^ 1, 0, alo); readB(cur ^ 1, 0, blo);
      __builtin_amdgcn_sched_barrier(0);
    }
    mmaq(ahi, bhi, 1, 1);                          // P3 (hi,hi) — disjoint from preloads
  }

  // ---- epilogue
  float wdeq = wsc[widx];
#pragma unroll
  for (int mf = 0; mf < 8; mf++) {
#pragma unroll
    for (int reg = 0; reg < 4; reg++) {
      int r = bm * 256 + wm * 128 + mf * 16 + lhi * 4 + reg;
      float deq = rowscale[r] * wdeq;
#pragma unroll
      for (int nf = 0; nf < 4; nf++) {
        int c = bn * 256 + wn * 64 + nf * 16 + llo;
        float val = acc[mf][nf][reg] * deq;
        if (EPI == 0) {
          float g = 0.5f * val * (1.0f + erff(val * 0.70710678118654752440f));
          ((u16*)outp)[(size_t)r * N + c] = f2h(g);
        } else {
          ((float*)outp)[(size_t)r * N + c] = val;
        }
      }
    }
  }
}

// ---------- 5. per-row norm + quant of h (f16 in, bf16-int out, in place) ----------
__global__ __launch_bounds__(256) void quant_h_kernel(u16* __restrict__ h, float* __restrict__ invs) {
  const int D = 8192;
  int row = blockIdx.x, tid = threadIdx.x;
  u16* hr = h + (size_t)row * D;
  float v[32];
#pragma unroll
  for (int j = 0; j < 4; j++) {
    u16x8 u = *(const u16x8*)&hr[j * 2048 + tid * 8];
#pragma unroll
    for (int e = 0; e < 8; e++) v[j * 8 + e] = h2f(u[e]);
  }
  double ss = 0; float mx = 0.0f;
#pragma unroll
  for (int i = 0; i < 32; i++) { ss += (double)v[i] * v[i]; mx = fmaxf(mx, fabsf(v[i])); }
  __shared__ double sd[256]; __shared__ float sf[256];
  sd[tid] = ss; sf[tid] = mx; __syncthreads();
  for (int o = 128; o > 0; o >>= 1) {
    if (tid < o) { sd[tid] += sd[tid + o]; sf[tid] = fmaxf(sf[tid], sf[tid + o]); }
    __syncthreads();
  }
  __shared__ float bn, bs;
  if (tid == 0) {
    float n = fmaxf((float)sqrt(sd[0]), 1e-12f);
    float amax = sf[0] * (sqrtf((float)D) / n);
    float cl = fmaxf(amax, 1e-5f);
    bn = n; bs = 127.0f / cl;
    invs[row] = cl / 127.0f;
  }
  __syncthreads();
  float n = bn, s = bs, sq = sqrtf((float)D);
#pragma unroll
  for (int j = 0; j < 4; j++) {
    u16x8 q;
#pragma unroll
    for (int e = 0; e < 8; e++) {
      float xn = (v[j * 8 + e] / n) * sq;
      float r = rintf(xn * s);
      r = fminf(fmaxf(r, -128.0f), 127.0f);
      q[e] = f2bf(r);
    }
    *(u16x8*)&hr[j * 2048 + tid * 8] = q;
  }
}

// ---------- launch ----------
extern "C" void kernel_launch(void* const* d_in, const int* in_sizes, int n_in,
                              void* d_out, int out_size, void* d_ws, size_t ws_size,
                              hipStream_t stream) {
  const float* x  = (const float*)d_in[0];   // [4,2048,2048] f32
  const float* w1 = (const float*)d_in[1];   // [8192,2048]   f32
  const float* w2 = (const float*)d_in[2];   // [2048,8192]   f32

  char* ws = (char*)d_ws;
  u16*    qx     = (u16*)(ws + 0);             // 8192x2048 bf16  (32 MB)
  u16*    w1q    = (u16*)(ws + 33554432);      // 8192x2048 bf16  (32 MB)
  u16*    w2q    = (u16*)(ws + 67108864);      // 2048x8192 bf16  (32 MB)
  u16*    h      = (u16*)(ws + 100663296);     // 8192x8192 f16 -> bf16-int (128 MB)
  float*  invs_x = (float*)(ws + 234881024);   // 8192 f32
  float*  invs_h = (float*)(ws + 234913792);   // 8192 f32
  double* part   = (double*)(ws + 234946560);  // 1024 f64
  float*  wsc    = (float*)(ws + 234954752);   // 4 f32: {1/d1, d1, 1/d2, d2}

  quant_x_kernel<<<8192, 256, 0, stream>>>(x, qx, invs_x);
  absum_partial<<<512, 256, 0, stream>>>(w1, part, 4194304);
  absum_partial<<<512, 256, 0, stream>>>(w2, part + 512, 4194304);
  wscale_final<<<1, 256, 0, stream>>>(part, wsc);
  quant_w_kernel<<<2048, 256, 0, stream>>>(w1, w1q, wsc, 0, 4194304);
  quant_w_kernel<<<2048, 256, 0, stream>>>(w2, w2q, wsc, 2, 4194304);
  gemm_fi<0><<<1024, 512, 0, stream>>>(qx, w1q, 8192, 2048, 32, invs_x, wsc, 1, (void*)h);
  quant_h_kernel<<<8192, 256, 0, stream>>>(h, invs_h);
  gemm_fi<1><<<256, 512, 0, stream>>>(h, w2q, 2048, 8192, 8, invs_h, wsc, 3, d_out);
}

// Round 9
// 457.631 us; speedup vs baseline: 1.4230x; 1.4230x over previous
//
#include <hip/hip_runtime.h>
#include <hip/hip_bf16.h>
#include <hip/hip_fp16.h>

typedef __attribute__((ext_vector_type(4))) int i32x4;
typedef __attribute__((ext_vector_type(8))) unsigned short u16x8;
typedef __attribute__((ext_vector_type(8))) char c8;
typedef __attribute__((ext_vector_type(4))) char c4;
typedef unsigned int u32;
typedef unsigned short u16;

#define SCH0() __builtin_amdgcn_sched_barrier(0)

// ---------- helpers ----------
__device__ __forceinline__ void gload_lds16(const void* g, void* l) {
  __builtin_amdgcn_global_load_lds((const u32 __attribute__((address_space(1)))*)g,
                                   (u32 __attribute__((address_space(3)))*)l, 16, 0, 0);
}
__device__ __forceinline__ float h2f(u16 u) { return __half2float(__ushort_as_half(u)); }
__device__ __forceinline__ u16  f2h(float f){ return __half_as_ushort(__float2half_rn(f)); }

// ---------- 1. per-token RMS-norm + absmax int8 quant of x ----------
__global__ __launch_bounds__(256) void quant_x_kernel(const float* __restrict__ x,
    char* __restrict__ qx, float* __restrict__ invs) {
  const int D = 2048;
  int row = blockIdx.x, tid = threadIdx.x;
  const float* xr = x + (size_t)row * D;
  float4 a = ((const float4*)xr)[tid * 2], b = ((const float4*)xr)[tid * 2 + 1];
  float v[8] = {a.x, a.y, a.z, a.w, b.x, b.y, b.z, b.w};
  double ss = 0; float mx = 0.0f;
#pragma unroll
  for (int i = 0; i < 8; i++) { ss += (double)v[i] * v[i]; mx = fmaxf(mx, fabsf(v[i])); }
  __shared__ double sd[256]; __shared__ float sf[256];
  sd[tid] = ss; sf[tid] = mx; __syncthreads();
  for (int o = 128; o > 0; o >>= 1) {
    if (tid < o) { sd[tid] += sd[tid + o]; sf[tid] = fmaxf(sf[tid], sf[tid + o]); }
    __syncthreads();
  }
  __shared__ float bn, bs;
  if (tid == 0) {
    float n = fmaxf((float)sqrt(sd[0]), 1e-12f);
    float amax = sf[0] * (sqrtf((float)D) / n);
    float cl = fmaxf(amax, 1e-5f);
    bn = n; bs = 127.0f / cl;
    invs[row] = cl / 127.0f;
  }
  __syncthreads();
  float n = bn, s = bs, sq = sqrtf((float)D);
  c8 q;
#pragma unroll
  for (int i = 0; i < 8; i++) {
    float xn = (v[i] / n) * sq;
    float r = rintf(xn * s);
    r = fminf(fmaxf(r, -128.0f), 127.0f);
    q[i] = (char)(int)r;
  }
  *(c8*)&qx[(size_t)row * D + tid * 8] = q;
}

// ---------- 2. deterministic sum(|w|) partials ----------
__global__ __launch_bounds__(256) void absum_partial(const float* __restrict__ w,
    double* __restrict__ part, int n4) {
  int tid = threadIdx.x;
  double s = 0;
  for (int i = blockIdx.x * 256 + tid; i < n4; i += gridDim.x * 256) {
    float4 v = ((const float4*)w)[i];
    s += (double)fabsf(v.x) + (double)fabsf(v.y) + (double)fabsf(v.z) + (double)fabsf(v.w);
  }
  __shared__ double sd[256];
  sd[tid] = s; __syncthreads();
  for (int o = 128; o > 0; o >>= 1) { if (tid < o) sd[tid] += sd[tid + o]; __syncthreads(); }
  if (tid == 0) part[blockIdx.x] = sd[0];
}

__global__ __launch_bounds__(256) void wscale_final(const double* __restrict__ part,
    float* __restrict__ wsc) {
  int tid = threadIdx.x;
  __shared__ double sd[256];
  sd[tid] = part[tid] + part[tid + 256]; __syncthreads();
  for (int o = 128; o > 0; o >>= 1) { if (tid < o) sd[tid] += sd[tid + o]; __syncthreads(); }
  double s1 = sd[0]; __syncthreads();
  sd[tid] = part[512 + tid] + part[768 + tid]; __syncthreads();
  for (int o = 128; o > 0; o >>= 1) { if (tid < o) sd[tid] += sd[tid + o]; __syncthreads(); }
  if (tid == 0) {
    float m1 = (float)(s1 / 16777216.0);
    float m2 = (float)(sd[0] / 16777216.0);
    float d1 = fmaxf(m1, 1e-5f), d2 = fmaxf(m2, 1e-5f);
    wsc[0] = 1.0f / d1; wsc[1] = d1; wsc[2] = 1.0f / d2; wsc[3] = d2;
  }
}

// ---------- 3. ternary weight quant (stored as i8 {-1,0,1}) ----------
__global__ __launch_bounds__(256) void quant_w_kernel(const float* __restrict__ w,
    char* __restrict__ q, const float* __restrict__ wsc, int widx, int n4) {
  float s = wsc[widx];
  for (int i = blockIdx.x * 256 + threadIdx.x; i < n4; i += gridDim.x * 256) {
    float4 v = ((const float4*)w)[i];
    c4 o;
    o[0] = (char)(int)(fminf(fmaxf(rintf(v.x * s), -1.0f), 1.0f));
    o[1] = (char)(int)(fminf(fmaxf(rintf(v.y * s), -1.0f), 1.0f));
    o[2] = (char)(int)(fminf(fmaxf(rintf(v.z * s), -1.0f), 1.0f));
    o[3] = (char)(int)(fminf(fmaxf(rintf(v.w * s), -1.0f), 1.0f));
    ((c4*)q)[i] = o;
  }
}

// ---------- 4. 256x256 i8 GEMM, r7 skeleton (batch-granular vmcnt ledger) ----------
// A[M][K] x B[N][K], i8, i32 accum (exact). Wave grid 2Mx4N, per-wave 128x64, BK=64.
// mfma_i32_16x16x64_i8: one MFMA covers the full K-tile per frag-pair (32/tile/wave).
// LDS [row][64B] per half-tile, 16B-block XOR swizzle kb ^= (row>>1)&3 (2-way max).
// Per tile t: readB(hi) | Q0 | readA(hi) | Q1 | lgkm(0)+bar | stage(t+2)x4 | Q2 |
// vmcnt(4|0)+bar | preload alo/blo(t+1) | Q3(ahi,bhi).
// EPI==0: dequant + exact GELU -> f16 store.  EPI==1: dequant -> f32 store.
template <int EPI>
__global__ __launch_bounds__(512, 2) void gemm_i8(const char* __restrict__ A,
    const char* __restrict__ B, int N, int K, size_t ldA, size_t ldB, int gridN,
    const float* __restrict__ rowscale, const float* __restrict__ wsc,
    int widx, void* __restrict__ outp) {
  __shared__ __align__(16) char sm[2][2][16384];   // [buf][mat][128x64 x2 halves] = 64 KiB
  const int tid = threadIdx.x;
  const int lane = tid & 63, w = tid >> 6;
  const int wm = w >> 2, wn = w & 3;               // 2M x 4N wave grid
  const int llo = lane & 15, lhi = lane >> 4;
  const int koff = ((lhi ^ ((llo >> 1) & 3)) << 4); // read-side swizzled 16B-block offset

  // T1: bijective XCD swizzle (gridDim.x % 8 == 0)
  const int nwg = gridDim.x, cpx = nwg >> 3;
  const int swz = (blockIdx.x & 7) * cpx + (blockIdx.x >> 3);
  const int bm = swz / gridN, bn = swz % gridN;

  const int NT = K >> 6;
  const size_t Abase = (size_t)(bm * 256) * ldA;
  const size_t Bbase = (size_t)(bn * 256) * ldB;

  // staging: thread covers one 16B block (row = tid>>2, kb = tid&3), inverse-swizzled source
  const int rs = tid >> 2;
  const int kbs = (((tid & 3) ^ ((tid >> 3) & 3)) << 4);

  auto stage = [&](int mat, int buf, int hf, int kt) {
    const char* G = (mat == 0) ? A : B;
    size_t ld = (mat == 0) ? ldA : ldB;
    size_t base = (mat == 0) ? Abase : Bbase;
    gload_lds16(G + base + (size_t)(hf * 128 + rs) * ld + (size_t)kt * 64 + kbs,
                &sm[buf][mat][hf * 8192 + tid * 16]);
  };

  i32x4 alo[4], ahi[4], blo[2], bhi[2];
  auto readA = [&](int buf, int half, i32x4 (&dst)[4]) {
    int rbase = wm * 128 + half * 64 + llo;
#pragma unroll
    for (int f = 0; f < 4; f++)
      dst[f] = *(const i32x4*)&sm[buf][0][(rbase + f * 16) * 64 + koff];
  };
  auto readB = [&](int buf, int half, i32x4 (&dst)[2]) {
    int rbase = wn * 64 + half * 32 + llo;
#pragma unroll
    for (int f = 0; f < 2; f++)
      dst[f] = *(const i32x4*)&sm[buf][1][(rbase + f * 16) * 64 + koff];
  };

  i32x4 acc[8][4];
#pragma unroll
  for (int m = 0; m < 8; m++)
#pragma unroll
    for (int n = 0; n < 4; n++) acc[m][n] = (i32x4){0, 0, 0, 0};

  auto mmaq = [&](i32x4 (&av)[4], i32x4 (&bv)[2], int mh, int nh) {
    __builtin_amdgcn_s_setprio(1);
#pragma unroll
    for (int m = 0; m < 4; m++)
#pragma unroll
      for (int n = 0; n < 2; n++)
        acc[mh * 4 + m][nh * 2 + n] =
            __builtin_amdgcn_mfma_i32_16x16x64_i8(av[m], bv[n],
                                                  acc[mh * 4 + m][nh * 2 + n], 0, 0, 0);
    __builtin_amdgcn_s_setprio(0);
  };

  // prologue: tile0 batch (4 loads), fence, tile1 batch (4); retire tile0 whole.
  stage(0, 0, 0, 0); stage(1, 0, 0, 0); stage(0, 0, 1, 0); stage(1, 0, 1, 0);
  asm volatile("s_nop 0" ::: "memory");            // batch boundary fence
  stage(0, 1, 0, 1); stage(1, 1, 0, 1); stage(0, 1, 1, 1); stage(1, 1, 1, 1);
  asm volatile("s_waitcnt vmcnt(4)\n\ts_barrier" ::: "memory");   // tile0 fully in LDS
  readA(0, 0, alo); readB(0, 0, blo);              // first-half operands of tile 0

  for (int t = 0; t < NT; t++) {
    const int cur = t & 1;
    readB(cur, 1, bhi);                            // 2 reads under Q0
    SCH0();
    mmaq(alo, blo, 0, 0);                          // Q0 (lo,lo)
    SCH0();
    readA(cur, 1, ahi);                            // 4 reads under Q1
    SCH0();
    mmaq(alo, bhi, 0, 1);                          // Q1 (lo,hi)
    // all reads of buf[cur] drained across all waves before anyone overwrites it
    asm volatile("s_waitcnt lgkmcnt(0)\n\ts_barrier" ::: "memory");
    if (t + 2 < NT) {                              // stage tile t+2 (4 loads, any order)
      stage(0, cur, 0, t + 2); stage(1, cur, 0, t + 2);
      stage(0, cur, 1, t + 2); stage(1, cur, 1, t + 2);
    }
    mmaq(ahi, blo, 1, 0);                          // Q2 (hi,lo) — last use of blo
    SCH0();
    if (t + 1 < NT) {                              // retire batch t+1 as a whole
      if (t + 2 < NT) asm volatile("s_waitcnt vmcnt(4)\n\ts_barrier" ::: "memory");
      else            asm volatile("s_waitcnt vmcnt(0)\n\ts_barrier" ::: "memory");
      // next-tile first-half operands, in flight under Q3
      readA(cur ^ 1, 0, alo); readB(cur ^ 1, 0, blo);
      SCH0();
    }
    mmaq(ahi, bhi, 1, 1);                          // Q3 (hi,hi) — disjoint from preloads
  }

  // ---- epilogue (i32 -> f32 exact, |acc| << 2^24)
  float wdeq = wsc[widx];
#pragma unroll
  for (int mf = 0; mf < 8; mf++) {
#pragma unroll
    for (int reg = 0; reg < 4; reg++) {
      int r = bm * 256 + wm * 128 + mf * 16 + lhi * 4 + reg;
      float deq = rowscale[r] * wdeq;
#pragma unroll
      for (int nf = 0; nf < 4; nf++) {
        int c = bn * 256 + wn * 64 + nf * 16 + llo;
        float val = (float)acc[mf][nf][reg] * deq;
        if (EPI == 0) {
          float g = 0.5f * val * (1.0f + erff(val * 0.70710678118654752440f));
          ((u16*)outp)[(size_t)r * N + c] = f2h(g);
        } else {
          ((float*)outp)[(size_t)r * N + c] = val;
        }
      }
    }
  }
}

// ---------- 5. per-row norm + quant of h: f16 in, i8 out IN-PLACE (first half of row) ----------
__global__ __launch_bounds__(256) void quant_h_kernel(u16* __restrict__ h, float* __restrict__ invs) {
  const int D = 8192;
  int row = blockIdx.x, tid = threadIdx.x;
  u16* hr = h + (size_t)row * D;
  float v[32];
#pragma unroll
  for (int j = 0; j < 4; j++) {
    u16x8 u = *(const u16x8*)&hr[j * 2048 + tid * 8];
#pragma unroll
    for (int e = 0; e < 8; e++) v[j * 8 + e] = h2f(u[e]);
  }
  double ss = 0; float mx = 0.0f;
#pragma unroll
  for (int i = 0; i < 32; i++) { ss += (double)v[i] * v[i]; mx = fmaxf(mx, fabsf(v[i])); }
  __shared__ double sd[256]; __shared__ float sf[256];
  sd[tid] = ss; sf[tid] = mx; __syncthreads();
  for (int o = 128; o > 0; o >>= 1) {
    if (tid < o) { sd[tid] += sd[tid + o]; sf[tid] = fmaxf(sf[tid], sf[tid + o]); }
    __syncthreads();
  }
  __shared__ float bn, bs;
  if (tid == 0) {
    float n = fmaxf((float)sqrt(sd[0]), 1e-12f);
    float amax = sf[0] * (sqrtf((float)D) / n);
    float cl = fmaxf(amax, 1e-5f);
    bn = n; bs = 127.0f / cl;
    invs[row] = cl / 127.0f;
  }
  __syncthreads();
  float n = bn, s = bs, sq = sqrtf((float)D);
  char* hq = (char*)hr;                     // i8 lands in the first 8192 B of this row
#pragma unroll
  for (int j = 0; j < 4; j++) {
    c8 q;
#pragma unroll
    for (int e = 0; e < 8; e++) {
      float xn = (v[j * 8 + e] / n) * sq;
      float r = rintf(xn * s);
      r = fminf(fmaxf(r, -128.0f), 127.0f);
      q[e] = (char)(int)r;
    }
    *(c8*)&hq[j * 2048 + tid * 8] = q;
  }
}

// ---------- launch ----------
extern "C" void kernel_launch(void* const* d_in, const int* in_sizes, int n_in,
                              void* d_out, int out_size, void* d_ws, size_t ws_size,
                              hipStream_t stream) {
  const float* x  = (const float*)d_in[0];   // [4,2048,2048] f32
  const float* w1 = (const float*)d_in[1];   // [8192,2048]   f32
  const float* w2 = (const float*)d_in[2];   // [2048,8192]   f32

  char* ws = (char*)d_ws;
  char*   qx     = (char*)(ws + 0);            // 8192x2048 i8   (16.8 MB)
  char*   w1q    = (char*)(ws + 16777216);     // 8192x2048 i8   (16.8 MB)
  char*   w2q    = (char*)(ws + 33554432);     // 2048x8192 i8   (16.8 MB)
  u16*    h      = (u16*)(ws + 50331648);      // 8192x8192 f16; i8 in-place after quant (128 MB)
  float*  invs_x = (float*)(ws + 184549376);   // 8192 f32
  float*  invs_h = (float*)(ws + 184582144);   // 8192 f32
  double* part   = (double*)(ws + 184614912);  // 1024 f64
  float*  wsc    = (float*)(ws + 184623104);   // 4 f32: {1/d1, d1, 1/d2, d2}

  quant_x_kernel<<<8192, 256, 0, stream>>>(x, qx, invs_x);
  absum_partial<<<512, 256, 0, stream>>>(w1, part, 4194304);
  absum_partial<<<512, 256, 0, stream>>>(w2, part + 512, 4194304);
  wscale_final<<<1, 256, 0, stream>>>(part, wsc);
  quant_w_kernel<<<2048, 256, 0, stream>>>(w1, w1q, wsc, 0, 4194304);
  quant_w_kernel<<<2048, 256, 0, stream>>>(w2, w2q, wsc, 2, 4194304);
  gemm_i8<0><<<1024, 512, 0, stream>>>(qx, w1q, 8192, 2048, 2048, 2048, 32,
                                       invs_x, wsc, 1, (void*)h);
  quant_h_kernel<<<8192, 256, 0, stream>>>(h, invs_h);
  gemm_i8<1><<<256, 512, 0, stream>>>((const char*)h, w2q, 2048, 8192, 16384, 8192, 8,
                                      invs_h, wsc, 3, d_out);
}

// Round 10
// 452.451 us; speedup vs baseline: 1.4393x; 1.0114x over previous
//
#include <hip/hip_runtime.h>
#include <hip/hip_bf16.h>
#include <hip/hip_fp16.h>

typedef __attribute__((ext_vector_type(4))) int i32x4;
typedef __attribute__((ext_vector_type(8))) unsigned short u16x8;
typedef __attribute__((ext_vector_type(8))) char c8;
typedef __attribute__((ext_vector_type(4))) char c4;
typedef unsigned int u32;
typedef unsigned short u16;

#define SCH0() __builtin_amdgcn_sched_barrier(0)

// ---------- helpers ----------
__device__ __forceinline__ void gload_lds16(const void* g, void* l) {
  __builtin_amdgcn_global_load_lds((const u32 __attribute__((address_space(1)))*)g,
                                   (u32 __attribute__((address_space(3)))*)l, 16, 0, 0);
}
__device__ __forceinline__ float h2f(u16 u) { return __half2float(__ushort_as_half(u)); }
__device__ __forceinline__ u16  f2h(float f){ return __half_as_ushort(__float2half_rn(f)); }

// ---------- 1. per-token RMS-norm + absmax int8 quant of x ----------
__global__ __launch_bounds__(256) void quant_x_kernel(const float* __restrict__ x,
    char* __restrict__ qx, float* __restrict__ invs) {
  const int D = 2048;
  int row = blockIdx.x, tid = threadIdx.x;
  const float* xr = x + (size_t)row * D;
  float4 a = ((const float4*)xr)[tid * 2], b = ((const float4*)xr)[tid * 2 + 1];
  float v[8] = {a.x, a.y, a.z, a.w, b.x, b.y, b.z, b.w};
  double ss = 0; float mx = 0.0f;
#pragma unroll
  for (int i = 0; i < 8; i++) { ss += (double)v[i] * v[i]; mx = fmaxf(mx, fabsf(v[i])); }
  __shared__ double sd[256]; __shared__ float sf[256];
  sd[tid] = ss; sf[tid] = mx; __syncthreads();
  for (int o = 128; o > 0; o >>= 1) {
    if (tid < o) { sd[tid] += sd[tid + o]; sf[tid] = fmaxf(sf[tid], sf[tid + o]); }
    __syncthreads();
  }
  __shared__ float bn, bs;
  if (tid == 0) {
    float n = fmaxf((float)sqrt(sd[0]), 1e-12f);
    float amax = sf[0] * (sqrtf((float)D) / n);
    float cl = fmaxf(amax, 1e-5f);
    bn = n; bs = 127.0f / cl;
    invs[row] = cl / 127.0f;
  }
  __syncthreads();
  float n = bn, s = bs, sq = sqrtf((float)D);
  c8 q;
#pragma unroll
  for (int i = 0; i < 8; i++) {
    float xn = (v[i] / n) * sq;
    float r = rintf(xn * s);
    r = fminf(fmaxf(r, -128.0f), 127.0f);
    q[i] = (char)(int)r;
  }
  *(c8*)&qx[(size_t)row * D + tid * 8] = q;
}

// ---------- 2. deterministic sum(|w|) partials ----------
__global__ __launch_bounds__(256) void absum_partial(const float* __restrict__ w,
    double* __restrict__ part, int n4) {
  int tid = threadIdx.x;
  double s = 0;
  for (int i = blockIdx.x * 256 + tid; i < n4; i += gridDim.x * 256) {
    float4 v = ((const float4*)w)[i];
    s += (double)fabsf(v.x) + (double)fabsf(v.y) + (double)fabsf(v.z) + (double)fabsf(v.w);
  }
  __shared__ double sd[256];
  sd[tid] = s; __syncthreads();
  for (int o = 128; o > 0; o >>= 1) { if (tid < o) sd[tid] += sd[tid + o]; __syncthreads(); }
  if (tid == 0) part[blockIdx.x] = sd[0];
}

__global__ __launch_bounds__(256) void wscale_final(const double* __restrict__ part,
    float* __restrict__ wsc) {
  int tid = threadIdx.x;
  __shared__ double sd[256];
  sd[tid] = part[tid] + part[tid + 256]; __syncthreads();
  for (int o = 128; o > 0; o >>= 1) { if (tid < o) sd[tid] += sd[tid + o]; __syncthreads(); }
  double s1 = sd[0]; __syncthreads();
  sd[tid] = part[512 + tid] + part[768 + tid]; __syncthreads();
  for (int o = 128; o > 0; o >>= 1) { if (tid < o) sd[tid] += sd[tid + o]; __syncthreads(); }
  if (tid == 0) {
    float m1 = (float)(s1 / 16777216.0);
    float m2 = (float)(sd[0] / 16777216.0);
    float d1 = fmaxf(m1, 1e-5f), d2 = fmaxf(m2, 1e-5f);
    wsc[0] = 1.0f / d1; wsc[1] = d1; wsc[2] = 1.0f / d2; wsc[3] = d2;
  }
}

// ---------- 3. ternary weight quant (stored as i8 {-1,0,1}) ----------
__global__ __launch_bounds__(256) void quant_w_kernel(const float* __restrict__ w,
    char* __restrict__ q, const float* __restrict__ wsc, int widx, int n4) {
  float s = wsc[widx];
  for (int i = blockIdx.x * 256 + threadIdx.x; i < n4; i += gridDim.x * 256) {
    float4 v = ((const float4*)w)[i];
    c4 o;
    o[0] = (char)(int)(fminf(fmaxf(rintf(v.x * s), -1.0f), 1.0f));
    o[1] = (char)(int)(fminf(fmaxf(rintf(v.y * s), -1.0f), 1.0f));
    o[2] = (char)(int)(fminf(fmaxf(rintf(v.z * s), -1.0f), 1.0f));
    o[3] = (char)(int)(fminf(fmaxf(rintf(v.w * s), -1.0f), 1.0f));
    ((c4*)q)[i] = o;
  }
}

// ---------- 4. 256x256 i8 GEMM, 3-buffer rotation, ONE fused barrier per K-tile ----------
// A[M][K] x B[N][K], i8, i32 accum (exact). Waves 2Mx4N, per-wave 128x64, BK=64.
// Buffers rotate R=t%3; stage target (t+2)%3 was last READ at tile t-1, so its
// WAR edge is closed by the PREVIOUS tile's fused lgkmcnt(0)+s_barrier — no
// mid-tile fence needed.  Per tile:
//   stage(t+2) at top | readB-hi, Q0, readA-hi, Q1, Q2 |
//   fused vmcnt(4|0)+lgkmcnt(0)+s_barrier | preload alo/blo(t+1) | Q3.
// vmcnt stays whole-batch (outstanding = stage(t+1)+stage(t+2) = 8 -> vmcnt(4)
// retires exactly stage(t+1); vmcnt(0) at t=NT-2).  Proven r5/r7 semantics.
// EPI==0: dequant + exact GELU -> f16 store.  EPI==1: dequant -> f32 store.
template <int EPI>
__global__ __launch_bounds__(512, 2) void gemm_i8(const char* __restrict__ A,
    const char* __restrict__ B, int N, int K, size_t ldA, size_t ldB, int gridN,
    const float* __restrict__ rowscale, const float* __restrict__ wsc,
    int widx, void* __restrict__ outp) {
  __shared__ __align__(16) char sm[3][2][16384];   // [buf][mat][2 halves x 128x64B] = 96 KiB
  const int tid = threadIdx.x;
  const int lane = tid & 63, w = tid >> 6;
  const int wm = w >> 2, wn = w & 3;               // 2M x 4N wave grid
  const int llo = lane & 15, lhi = lane >> 4;
  const int koff = ((lhi ^ ((llo >> 1) & 3)) << 4); // read-side swizzled 16B-block offset

  // T1: bijective XCD swizzle (gridDim.x % 8 == 0)
  const int nwg = gridDim.x, cpx = nwg >> 3;
  const int swz = (blockIdx.x & 7) * cpx + (blockIdx.x >> 3);
  const int bm = swz / gridN, bn = swz % gridN;

  const int NT = K >> 6;
  const size_t Abase = (size_t)(bm * 256) * ldA;
  const size_t Bbase = (size_t)(bn * 256) * ldB;

  // staging: thread covers one 16B block (row = tid>>2, kb = tid&3), inverse-swizzled source
  const int rs = tid >> 2;
  const int kbs = (((tid & 3) ^ ((tid >> 3) & 3)) << 4);

  auto stage = [&](int mat, int buf, int hf, int kt) {
    const char* G = (mat == 0) ? A : B;
    size_t ld = (mat == 0) ? ldA : ldB;
    size_t base = (mat == 0) ? Abase : Bbase;
    gload_lds16(G + base + (size_t)(hf * 128 + rs) * ld + (size_t)kt * 64 + kbs,
                &sm[buf][mat][hf * 8192 + tid * 16]);
  };
  auto stage_tile = [&](int buf, int kt) {       // one whole K-tile = 4 loads/thread
    stage(0, buf, 0, kt); stage(1, buf, 0, kt);
    stage(0, buf, 1, kt); stage(1, buf, 1, kt);
  };

  i32x4 alo[4], ahi[4], blo[2], bhi[2];
  auto readA = [&](int buf, int half, i32x4 (&dst)[4]) {
    int rbase = wm * 128 + half * 64 + llo;
#pragma unroll
    for (int f = 0; f < 4; f++)
      dst[f] = *(const i32x4*)&sm[buf][0][(rbase + f * 16) * 64 + koff];
  };
  auto readB = [&](int buf, int half, i32x4 (&dst)[2]) {
    int rbase = wn * 64 + half * 32 + llo;
#pragma unroll
    for (int f = 0; f < 2; f++)
      dst[f] = *(const i32x4*)&sm[buf][1][(rbase + f * 16) * 64 + koff];
  };

  i32x4 acc[8][4];
#pragma unroll
  for (int m = 0; m < 8; m++)
#pragma unroll
    for (int n = 0; n < 4; n++) acc[m][n] = (i32x4){0, 0, 0, 0};

  auto mmaq = [&](i32x4 (&av)[4], i32x4 (&bv)[2], int mh, int nh) {
    __builtin_amdgcn_s_setprio(1);
#pragma unroll
    for (int m = 0; m < 4; m++)
#pragma unroll
      for (int n = 0; n < 2; n++)
        acc[mh * 4 + m][nh * 2 + n] =
            __builtin_amdgcn_mfma_i32_16x16x64_i8(av[m], bv[n],
                                                  acc[mh * 4 + m][nh * 2 + n], 0, 0, 0);
    __builtin_amdgcn_s_setprio(0);
  };

  // prologue: tile0 -> buf0 (4 loads), fence, tile1 -> buf1 (4); retire tile0 whole.
  stage_tile(0, 0);
  asm volatile("s_nop 0" ::: "memory");            // batch boundary fence
  stage_tile(1, 1);
  asm volatile("s_waitcnt vmcnt(4)\n\ts_barrier" ::: "memory");   // tile0 resident; tile1 in flight
  readA(0, 0, alo); readB(0, 0, blo);              // first-half operands of tile 0

  int bR = 0, bN = 1, bS = 2;                       // read / next / stage-target buffers
  for (int t = 0; t < NT; t++) {
    if (t + 2 < NT) stage_tile(bS, t + 2);         // issued at tile top (max latency hiding)
    SCH0();
    readB(bR, 1, bhi);                             // 2 reads under Q0
    SCH0();
    mmaq(alo, blo, 0, 0);                          // Q0 (lo,lo)
    SCH0();
    readA(bR, 1, ahi);                             // 4 reads under Q1
    SCH0();
    mmaq(alo, bhi, 0, 1);                          // Q1 (lo,hi)
    mmaq(ahi, blo, 1, 0);                          // Q2 (hi,lo)
    SCH0();
    if (t + 1 < NT) {
      // ONE barrier per tile: retire stage(t+1) whole (vmcnt), drain this tile's
      // ds_reads (lgkm; WAR for next tile's stage into buf bR), then sync.
      if (t + 2 < NT) asm volatile("s_waitcnt vmcnt(4) lgkmcnt(0)\n\ts_barrier" ::: "memory");
      else            asm volatile("s_waitcnt vmcnt(0) lgkmcnt(0)\n\ts_barrier" ::: "memory");
      readA(bN, 0, alo); readB(bN, 0, blo);        // preload t+1 first halves under Q3
      SCH0();
    }
    mmaq(ahi, bhi, 1, 1);                          // Q3 (hi,hi) — disjoint from preloads
    int tmp = bR; bR = bN; bN = bS; bS = tmp;      // rotate buffers
  }

  // ---- epilogue (i32 -> f32 exact, |acc| << 2^24)
  float wdeq = wsc[widx];
#pragma unroll
  for (int mf = 0; mf < 8; mf++) {
#pragma unroll
    for (int reg = 0; reg < 4; reg++) {
      int r = bm * 256 + wm * 128 + mf * 16 + lhi * 4 + reg;
      float deq = rowscale[r] * wdeq;
#pragma unroll
      for (int nf = 0; nf < 4; nf++) {
        int c = bn * 256 + wn * 64 + nf * 16 + llo;
        float val = (float)acc[mf][nf][reg] * deq;
        if (EPI == 0) {
          float g = 0.5f * val * (1.0f + erff(val * 0.70710678118654752440f));
          ((u16*)outp)[(size_t)r * N + c] = f2h(g);
        } else {
          ((float*)outp)[(size_t)r * N + c] = val;
        }
      }
    }
  }
}

// ---------- 5. per-row norm + quant of h: f16 in, i8 out IN-PLACE (first half of row) ----------
__global__ __launch_bounds__(256) void quant_h_kernel(u16* __restrict__ h, float* __restrict__ invs) {
  const int D = 8192;
  int row = blockIdx.x, tid = threadIdx.x;
  u16* hr = h + (size_t)row * D;
  float v[32];
#pragma unroll
  for (int j = 0; j < 4; j++) {
    u16x8 u = *(const u16x8*)&hr[j * 2048 + tid * 8];
#pragma unroll
    for (int e = 0; e < 8; e++) v[j * 8 + e] = h2f(u[e]);
  }
  double ss = 0; float mx = 0.0f;
#pragma unroll
  for (int i = 0; i < 32; i++) { ss += (double)v[i] * v[i]; mx = fmaxf(mx, fabsf(v[i])); }
  __shared__ double sd[256]; __shared__ float sf[256];
  sd[tid] = ss; sf[tid] = mx; __syncthreads();
  for (int o = 128; o > 0; o >>= 1) {
    if (tid < o) { sd[tid] += sd[tid + o]; sf[tid] = fmaxf(sf[tid], sf[tid + o]); }
    __syncthreads();
  }
  __shared__ float bn, bs;
  if (tid == 0) {
    float n = fmaxf((float)sqrt(sd[0]), 1e-12f);
    float amax = sf[0] * (sqrtf((float)D) / n);
    float cl = fmaxf(amax, 1e-5f);
    bn = n; bs = 127.0f / cl;
    invs[row] = cl / 127.0f;
  }
  __syncthreads();
  float n = bn, s = bs, sq = sqrtf((float)D);
  char* hq = (char*)hr;                     // i8 lands in the first 8192 B of this row
#pragma unroll
  for (int j = 0; j < 4; j++) {
    c8 q;
#pragma unroll
    for (int e = 0; e < 8; e++) {
      float xn = (v[j * 8 + e] / n) * sq;
      float r = rintf(xn * s);
      r = fminf(fmaxf(r, -128.0f), 127.0f);
      q[e] = (char)(int)r;
    }
    *(c8*)&hq[j * 2048 + tid * 8] = q;
  }
}

// ---------- launch ----------
extern "C" void kernel_launch(void* const* d_in, const int* in_sizes, int n_in,
                              void* d_out, int out_size, void* d_ws, size_t ws_size,
                              hipStream_t stream) {
  const float* x  = (const float*)d_in[0];   // [4,2048,2048] f32
  const float* w1 = (const float*)d_in[1];   // [8192,2048]   f32
  const float* w2 = (const float*)d_in[2];   // [2048,8192]   f32

  char* ws = (char*)d_ws;
  char*   qx     = (char*)(ws + 0);            // 8192x2048 i8   (16.8 MB)
  char*   w1q    = (char*)(ws + 16777216);     // 8192x2048 i8   (16.8 MB)
  char*   w2q    = (char*)(ws + 33554432);     // 2048x8192 i8   (16.8 MB)
  u16*    h      = (u16*)(ws + 50331648);      // 8192x8192 f16; i8 in-place after quant (128 MB)
  float*  invs_x = (float*)(ws + 184549376);   // 8192 f32
  float*  invs_h = (float*)(ws + 184582144);   // 8192 f32
  double* part   = (double*)(ws + 184614912);  // 1024 f64
  float*  wsc    = (float*)(ws + 184623104);   // 4 f32: {1/d1, d1, 1/d2, d2}

  quant_x_kernel<<<8192, 256, 0, stream>>>(x, qx, invs_x);
  absum_partial<<<512, 256, 0, stream>>>(w1, part, 4194304);
  absum_partial<<<512, 256, 0, stream>>>(w2, part + 512, 4194304);
  wscale_final<<<1, 256, 0, stream>>>(part, wsc);
  quant_w_kernel<<<2048, 256, 0, stream>>>(w1, w1q, wsc, 0, 4194304);
  quant_w_kernel<<<2048, 256, 0, stream>>>(w2, w2q, wsc, 2, 4194304);
  gemm_i8<0><<<1024, 512, 0, stream>>>(qx, w1q, 8192, 2048, 2048, 2048, 32,
                                       invs_x, wsc, 1, (void*)h);
  quant_h_kernel<<<8192, 256, 0, stream>>>(h, invs_h);
  gemm_i8<1><<<256, 512, 0, stream>>>((const char*)h, w2q, 2048, 8192, 16384, 8192, 8,
                                      invs_h, wsc, 3, d_out);
}